// Round 7
// baseline (805.937 us; speedup 1.0000x reference)
//
#include <hip/hip_runtime.h>
#include <math.h>

// B=64, T=1000, S=96, A=32, INP=128, H=256. All I/O fp32.
// d_ws: pre fp16 [2][64000][256] = 65,536,000 B | h fp16 same = 65,536,000 B.
// W frag tables (393,216 B) live in the TAIL of the h region: ff reads them
// before rnn overwrites that region with h. Total ws use = 131,072,000 B.

typedef _Float16 half2_t __attribute__((ext_vector_type(2)));
typedef __attribute__((ext_vector_type(8))) short bf16x8;   // 8 bf16 in 4 VGPRs
typedef __attribute__((ext_vector_type(4))) float f32x4;

__device__ __forceinline__ float fdot2(half2_t a, half2_t b, float c) {
#if __has_builtin(__builtin_amdgcn_fdot2)
    return __builtin_amdgcn_fdot2(a, b, c, false);   // v_dot2_f32_f16
#else
    return c + (float)a[0] * (float)b[0] + (float)a[1] * (float)b[1];
#endif
}

__device__ __forceinline__ short f2bf(float f) {     // fp32 -> bf16 (RNE)
    unsigned u = __builtin_bit_cast(unsigned, f);
    return (short)((u + 0x7FFFu + ((u >> 16) & 1u)) >> 16);
}

// Barrier WITHOUT the vmcnt(0) drain __syncthreads() inserts. Safe when
// inter-wave communication is LDS-only (lgkmcnt covers DS ops).
__device__ __forceinline__ void barrier_lds() {
    __asm__ __volatile__("s_waitcnt lgkmcnt(0)" ::: "memory");
    __builtin_amdgcn_s_barrier();
}

// ---------------------------------------------------------------------------
// Kernel 0: pre-swizzle W into MFMA B-fragment tables (bf16).
// B-frag for mfma_f32_16x16x32_bf16: lane holds B[k = (lane>>4)*8 + j][n = lane&15]
// G1 entries: ((br*16+nt)*4+ks)*64+lane   (Wa: fc11_w/fc21_w, K=128)
// G2 entries: 8192 + ((br*16+nt)*8+ks)*64+lane (Wi: W_ih1/W_ih2, K=256)
// ---------------------------------------------------------------------------
__global__ __launch_bounds__(256, 1)
void prep_kernel(const float* __restrict__ fc11_w, const float* __restrict__ W_ih1,
                 const float* __restrict__ fc21_w, const float* __restrict__ W_ih2,
                 short* __restrict__ tab)
{
    const int e    = blockIdx.x * 256 + threadIdx.x;   // 96*256 = 24576 entries
    const int lane = e & 63;
    const int q = lane >> 4, m = lane & 15;
    const float* W;
    int k0, n;
    if (e < 8192) {                       // G1
        int t_ = e >> 6;
        int ks = t_ & 3, nt = (t_ >> 2) & 15, br = t_ >> 6;
        W = br ? fc21_w : fc11_w;
        k0 = ks * 32 + q * 8; n = nt * 16 + m;
    } else {                              // G2
        int t_ = (e - 8192) >> 6;
        int ks = t_ & 7, nt = (t_ >> 3) & 15, br = t_ >> 7;
        W = br ? W_ih2 : W_ih1;
        k0 = ks * 32 + q * 8; n = nt * 16 + m;
    }
    bf16x8 v;
#pragma unroll
    for (int j = 0; j < 8; ++j) v[j] = f2bf(W[(size_t)(k0 + j) * 256 + n]);
    ((bf16x8*)tab)[e] = v;
}

// ---------------------------------------------------------------------------
// Kernel 1: feed-forward via MFMA. Block = 64 rows; wave w owns rows
// [row0+16w, +16). GEMM1 (K=128): a-frags straight from global state/action.
// relu+bias -> bf16 X1 in LDS (row stride 264 = conflict-free frag reads).
// GEMM2 (K=256): a-frags from LDS (same-wave dependency -> no barrier).
// ---------------------------------------------------------------------------
__global__ __launch_bounds__(256, 2)
void ff_kernel(const float* __restrict__ state,
               const float* __restrict__ action,
               const float* __restrict__ fc11_b, const float* __restrict__ fc21_b,
               const float* __restrict__ b_hh1, const float* __restrict__ b_ih1,
               const float* __restrict__ b_hh2, const float* __restrict__ b_ih2,
               const short* __restrict__ tab,
               _Float16* __restrict__ pre_out)
{
    __shared__ short X1[64 * 264];        // 33.8 KB bf16, +8 pad per row

    const int tile = blockIdx.x % 1000;
    const int br   = blockIdx.x / 1000;
    const int tid  = threadIdx.x;
    const int w    = tid >> 6;
    const int lane = tid & 63;
    const int q = lane >> 4, m = lane & 15;
    const int row0 = tile * 64;
    const int rw   = row0 + 16 * w + m;   // a-frag row of this lane

    const float* ba = br ? fc21_b : fc11_b;
    const float* bh = br ? b_hh2 : b_hh1;
    const float* bi = br ? b_ih2 : b_ih1;
    const bf16x8* tG1 = (const bf16x8*)tab + (size_t)br * 4096;
    const bf16x8* tG2 = (const bf16x8*)tab + 8192 + (size_t)br * 8192;

    // per-lane bias values (col = nt*16 + m)
    float ba_v[16], bb_v[16];
#pragma unroll
    for (int nt = 0; nt < 16; ++nt) {
        int c = nt * 16 + m;
        ba_v[nt] = ba[c];
        bb_v[nt] = bh[c] + bi[c];
    }

    // GEMM1 a-frags from global X = concat(state[96], action[32])
    bf16x8 af[4];
#pragma unroll
    for (int ks = 0; ks < 4; ++ks) {
        int k0 = ks * 32 + q * 8;
        const float* src = (k0 < 96) ? (state  + (size_t)rw * 96 + k0)
                                     : (action + (size_t)rw * 32 + (k0 - 96));
        float4 x0 = *(const float4*)src;
        float4 x1 = *(const float4*)(src + 4);
        bf16x8 a;
        a[0] = f2bf(x0.x); a[1] = f2bf(x0.y); a[2] = f2bf(x0.z); a[3] = f2bf(x0.w);
        a[4] = f2bf(x1.x); a[5] = f2bf(x1.y); a[6] = f2bf(x1.z); a[7] = f2bf(x1.w);
        af[ks] = a;
    }

    // GEMM1: X1 = relu(X @ Wa + ba)
#pragma unroll
    for (int nt = 0; nt < 16; ++nt) {
        f32x4 acc = {0.f, 0.f, 0.f, 0.f};
#pragma unroll
        for (int ks = 0; ks < 4; ++ks)
            acc = __builtin_amdgcn_mfma_f32_16x16x32_bf16(
                      af[ks], tG1[(nt * 4 + ks) * 64 + lane], acc, 0, 0, 0);
#pragma unroll
        for (int r = 0; r < 4; ++r) {     // D: col=lane&15, row=q*4+r
            float v = acc[r] + ba_v[nt];
            v = v > 0.f ? v : 0.f;
            X1[(16 * w + q * 4 + r) * 264 + nt * 16 + m] = f2bf(v);
        }
    }
    // X1 rows [16w,16w+16) written and read by THIS wave only -> lgkmcnt
    // ordering suffices; no barrier.

    // GEMM2 a-frags from LDS
    bf16x8 a2[8];
#pragma unroll
    for (int ks = 0; ks < 8; ++ks)
        a2[ks] = *(const bf16x8*)&X1[(16 * w + m) * 264 + ks * 32 + q * 8];

    _Float16* pre = pre_out + (size_t)br * 64000u * 256u;
#pragma unroll
    for (int nt = 0; nt < 16; ++nt) {
        f32x4 acc = {0.f, 0.f, 0.f, 0.f};
#pragma unroll
        for (int ks = 0; ks < 8; ++ks)
            acc = __builtin_amdgcn_mfma_f32_16x16x32_bf16(
                      a2[ks], tG2[(nt * 8 + ks) * 64 + lane], acc, 0, 0, 0);
#pragma unroll
        for (int r = 0; r < 4; ++r) {
            float v = acc[r] + bb_v[nt];
            pre[(size_t)(row0 + 16 * w + q * 4 + r) * 256 + nt * 16 + m] = (_Float16)v;
        }
    }
}

// ---------------------------------------------------------------------------
// Kernel 2: recurrence, split-K across 4 waves, 128 blocks (1 wave/SIMD).
// CHANGE vs R6: weights are PINNED in VGPRs. R6's VGPR_Count=88 proved the
// compiler rematerialized the weight loads+cvt inside the step loop (per-step
// global reload of 256 B/thread + ~128 cvt ops = the missing ~700 cyc/step).
// The volatile "+v" asm below claims to write each weight register: the
// compiler cannot re-derive the value, so all 128 half2 stay live in VGPRs
// (budget 512/wave at 1 wave/SIMD).
// ---------------------------------------------------------------------------
__global__ __launch_bounds__(256, 1)
void rnn_kernel(const _Float16* __restrict__ pre_all,
                const float* __restrict__ hn,
                const float* __restrict__ W_hh1,
                const float* __restrict__ W_hh2,
                _Float16* __restrict__ h_out)
{
    __shared__ _Float16 hbuf[256];
    __shared__ float part[2][4][256];   // [parity][wave][col] = 8 KB

    const int wg = blockIdx.x;          // 0..127
    const int br = wg >> 6;
    const int b  = wg & 63;
    const float* Whh = br ? W_hh2 : W_hh1;
    const _Float16* pre = pre_all + ((size_t)br * 64000u + (size_t)b * 1000u) * 256u;
    _Float16* hg = h_out + ((size_t)br * 64000u + (size_t)b * 1000u) * 256u;

    const int t  = threadIdx.x;
    const int w  = t >> 6;              // wave id = k-slice
    const int l  = t & 63;
    const int k0 = w * 64;
    const int c0 = l * 4;               // 4 columns per lane

    // weights: cols {c0..c0+3} x k in [k0,k0+64), half2 along k, stored as
    // bit-cast uint so the pinning asm constraint is a plain 32-bit VGPR
    unsigned whb[4][32];
#pragma unroll
    for (int i = 0; i < 32; ++i) {
        float4 lo = *(const float4*)(Whh + (size_t)(k0 + 2 * i) * 256 + c0);
        float4 hi = *(const float4*)(Whh + (size_t)(k0 + 2 * i + 1) * 256 + c0);
        whb[0][i] = __builtin_bit_cast(unsigned, half2_t{(_Float16)lo.x, (_Float16)hi.x});
        whb[1][i] = __builtin_bit_cast(unsigned, half2_t{(_Float16)lo.y, (_Float16)hi.y});
        whb[2][i] = __builtin_bit_cast(unsigned, half2_t{(_Float16)lo.z, (_Float16)hi.z});
        whb[3][i] = __builtin_bit_cast(unsigned, half2_t{(_Float16)lo.w, (_Float16)hi.w});
    }
    // PIN: volatile asm "writes" each value -> no remat, stays in a VGPR.
#pragma unroll
    for (int c = 0; c < 4; ++c)
#pragma unroll
        for (int i = 0; i < 32; ++i)
            __asm__ __volatile__("" : "+v"(whb[c][i]));

    hbuf[t] = (_Float16)hn[b * 256 + t];
    barrier_lds();

    float pre_c = (float)pre[t];
    float pre_n = (float)pre[256 + t];

    for (int tt = 0; tt < 1000; ++tt) {
        // issue t+2 prefetch early; stays in flight across the barrier
        const int t2 = (tt + 2 < 1000) ? (tt + 2) : 999;
        const float pre_n2 = (float)pre[(size_t)t2 * 256 + t];

        // partial dot over own k-slice, 4 cols, 2 accumulators each
        const float4* hb = (const float4*)&hbuf[k0];
        float sA0 = 0.f, sA1 = 0.f, sA2 = 0.f, sA3 = 0.f;
        float sB0 = 0.f, sB1 = 0.f, sB2 = 0.f, sB3 = 0.f;
#pragma unroll
        for (int k = 0; k < 8; ++k) {
            float4 v = hb[k];                       // 8 halves, wave-broadcast
            const half2_t* hh = (const half2_t*)&v;
#define WH(c, idx) __builtin_bit_cast(half2_t, whb[c][idx])
            sA0 = fdot2(hh[0], WH(0, 4 * k + 0), sA0);
            sA1 = fdot2(hh[0], WH(1, 4 * k + 0), sA1);
            sA2 = fdot2(hh[0], WH(2, 4 * k + 0), sA2);
            sA3 = fdot2(hh[0], WH(3, 4 * k + 0), sA3);
            sA0 = fdot2(hh[1], WH(0, 4 * k + 1), sA0);
            sA1 = fdot2(hh[1], WH(1, 4 * k + 1), sA1);
            sA2 = fdot2(hh[1], WH(2, 4 * k + 1), sA2);
            sA3 = fdot2(hh[1], WH(3, 4 * k + 1), sA3);
            sB0 = fdot2(hh[2], WH(0, 4 * k + 2), sB0);
            sB1 = fdot2(hh[2], WH(1, 4 * k + 2), sB1);
            sB2 = fdot2(hh[2], WH(2, 4 * k + 2), sB2);
            sB3 = fdot2(hh[2], WH(3, 4 * k + 2), sB3);
            sB0 = fdot2(hh[3], WH(0, 4 * k + 3), sB0);
            sB1 = fdot2(hh[3], WH(1, 4 * k + 3), sB1);
            sB2 = fdot2(hh[3], WH(2, 4 * k + 3), sB2);
            sB3 = fdot2(hh[3], WH(3, 4 * k + 3), sB3);
#undef WH
        }
        const int pp = tt & 1;
        *(float4*)&part[pp][w][c0] =
            float4{sA0 + sB0, sA1 + sB1, sA2 + sB2, sA3 + sB3};
        barrier_lds();                              // publish partials

        // reduce col t (wave w owns its own next-step slice)
        const float z = ((part[pp][0][t] + part[pp][1][t]) +
                         (part[pp][2][t] + part[pp][3][t])) + pre_c;
        const float h = 1.0f / (1.0f + __expf(-z));
        const _Float16 h16 = (_Float16)h;
        hbuf[t] = h16;                              // same-wave consumer
        hg[(size_t)tt * 256 + t] = h16;             // in flight across barrier

        pre_c = pre_n;
        pre_n = pre_n2;
    }
}

// ---------------------------------------------------------------------------
// Kernel 3: q head. q[n] = h[n,:] . qw + qb. One thread per output.
// ---------------------------------------------------------------------------
__global__ __launch_bounds__(256, 2)
void q_kernel(const _Float16* __restrict__ h_all,
              const float* __restrict__ fc12_w, const float* __restrict__ fc12_b,
              const float* __restrict__ fc22_w, const float* __restrict__ fc22_b,
              float* __restrict__ out)
{
    const int n  = blockIdx.x * 256 + threadIdx.x;    // 500 blocks -> n < 128000
    const int br = (n >= 64000);                      // block-uniform
    const float* qwp = br ? fc22_w : fc12_w;
    const float  qb  = br ? fc22_b[0] : fc12_b[0];

    half2_t qw[128];
#pragma unroll
    for (int i = 0; i < 128; ++i)
        qw[i] = half2_t{(_Float16)qwp[2 * i], (_Float16)qwp[2 * i + 1]};

    const float4* hr = (const float4*)(h_all + (size_t)n * 256u);
    float s0 = qb, s1 = 0.f, s2 = 0.f, s3 = 0.f;
#pragma unroll
    for (int k = 0; k < 32; ++k) {
        float4 v = hr[k];
        const half2_t* hh = (const half2_t*)&v;
        s0 = fdot2(hh[0], qw[4 * k + 0], s0);
        s1 = fdot2(hh[1], qw[4 * k + 1], s1);
        s2 = fdot2(hh[2], qw[4 * k + 2], s2);
        s3 = fdot2(hh[3], qw[4 * k + 3], s3);
    }
    out[n] = (s0 + s1) + (s2 + s3);
}

// ---------------------------------------------------------------------------
extern "C" void kernel_launch(void* const* d_in, const int* in_sizes, int n_in,
                              void* d_out, int out_size, void* d_ws, size_t ws_size,
                              hipStream_t stream)
{
    const float* state  = (const float*)d_in[0];
    const float* action = (const float*)d_in[1];
    const float* hn     = (const float*)d_in[2];
    const float* fc11_w = (const float*)d_in[3];
    const float* fc11_b = (const float*)d_in[4];
    const float* W_hh1  = (const float*)d_in[5];
    const float* W_ih1  = (const float*)d_in[6];
    const float* b_hh1  = (const float*)d_in[7];
    const float* b_ih1  = (const float*)d_in[8];
    const float* fc12_w = (const float*)d_in[9];
    const float* fc12_b = (const float*)d_in[10];
    const float* fc21_w = (const float*)d_in[11];
    const float* fc21_b = (const float*)d_in[12];
    const float* W_hh2  = (const float*)d_in[13];
    const float* W_ih2  = (const float*)d_in[14];
    const float* b_hh2  = (const float*)d_in[15];
    const float* b_ih2  = (const float*)d_in[16];
    const float* fc22_w = (const float*)d_in[17];
    const float* fc22_b = (const float*)d_in[18];

    _Float16* pre = (_Float16*)d_ws;                         // 65,536,000 B
    _Float16* hbg = (_Float16*)d_ws + 32768000u;             // 65,536,000 B
    short* tab = (short*)((char*)d_ws + 130678784u);         // frag tables (tail of h region)

    prep_kernel<<<96, 256, 0, stream>>>(fc11_w, W_ih1, fc21_w, W_ih2, tab);
    ff_kernel<<<2000, 256, 0, stream>>>(state, action,
                                        fc11_b, fc21_b, b_hh1, b_ih1,
                                        b_hh2, b_ih2, tab, pre);
    rnn_kernel<<<128, 256, 0, stream>>>(pre, hn, W_hh1, W_hh2, hbg);
    q_kernel<<<500, 256, 0, stream>>>(hbg, fc12_w, fc12_b, fc22_w, fc22_b,
                                      (float*)d_out);
}

// Round 8
// 756.757 us; speedup vs baseline: 1.0650x; 1.0650x over previous
//
#include <hip/hip_runtime.h>
#include <math.h>

// B=64, T=1000, S=96, A=32, INP=128, H=256. All I/O fp32.
// d_ws: pre fp16 [2][64000][256] = 65,536,000 B | h fp16 same = 65,536,000 B.
// W frag tables (393,216 B) live in the TAIL of the h region: ff reads them
// before rnn overwrites that region with h. Total ws use = 131,072,000 B.

typedef _Float16 half2_t __attribute__((ext_vector_type(2)));
typedef __attribute__((ext_vector_type(8))) short bf16x8;   // 8 bf16 in 4 VGPRs
typedef __attribute__((ext_vector_type(4))) float f32x4;

__device__ __forceinline__ float fdot2(half2_t a, half2_t b, float c) {
#if __has_builtin(__builtin_amdgcn_fdot2)
    return __builtin_amdgcn_fdot2(a, b, c, false);   // v_dot2_f32_f16
#else
    return c + (float)a[0] * (float)b[0] + (float)a[1] * (float)b[1];
#endif
}

__device__ __forceinline__ short f2bf(float f) {     // fp32 -> bf16 (RNE)
    unsigned u = __builtin_bit_cast(unsigned, f);
    return (short)((u + 0x7FFFu + ((u >> 16) & 1u)) >> 16);
}

// Barrier WITHOUT the vmcnt(0) drain __syncthreads() inserts. Safe when
// inter-wave communication is LDS-only (lgkmcnt covers DS ops).
__device__ __forceinline__ void barrier_lds() {
    __asm__ __volatile__("s_waitcnt lgkmcnt(0)" ::: "memory");
    __builtin_amdgcn_s_barrier();
}

// ---------------------------------------------------------------------------
// Kernel 0: pre-swizzle W into MFMA B-fragment tables (bf16).
// B-frag for mfma_f32_16x16x32_bf16: lane holds B[k = (lane>>4)*8 + j][n = lane&15]
// G1 entries: ((br*16+nt)*4+ks)*64+lane   (Wa: fc11_w/fc21_w, K=128)
// G2 entries: 8192 + ((br*16+nt)*8+ks)*64+lane (Wi: W_ih1/W_ih2, K=256)
// ---------------------------------------------------------------------------
__global__ __launch_bounds__(256, 1)
void prep_kernel(const float* __restrict__ fc11_w, const float* __restrict__ W_ih1,
                 const float* __restrict__ fc21_w, const float* __restrict__ W_ih2,
                 short* __restrict__ tab)
{
    const int e    = blockIdx.x * 256 + threadIdx.x;   // 96*256 = 24576 entries
    const int lane = e & 63;
    const int q = lane >> 4, m = lane & 15;
    const float* W;
    int k0, n;
    if (e < 8192) {                       // G1
        int t_ = e >> 6;
        int ks = t_ & 3, nt = (t_ >> 2) & 15, br = t_ >> 6;
        W = br ? fc21_w : fc11_w;
        k0 = ks * 32 + q * 8; n = nt * 16 + m;
    } else {                              // G2
        int t_ = (e - 8192) >> 6;
        int ks = t_ & 7, nt = (t_ >> 3) & 15, br = t_ >> 7;
        W = br ? W_ih2 : W_ih1;
        k0 = ks * 32 + q * 8; n = nt * 16 + m;
    }
    bf16x8 v;
#pragma unroll
    for (int j = 0; j < 8; ++j) v[j] = f2bf(W[(size_t)(k0 + j) * 256 + n]);
    ((bf16x8*)tab)[e] = v;
}

// ---------------------------------------------------------------------------
// Kernel 1: feed-forward via MFMA. CHANGE vs R7: 128-row blocks (grid 1000,
// 2 m-tiles per wave) — each B-frag load now feeds 2 m-tiles, halving the
// L2 b-frag traffic (was the ff bottleneck: 1.57 GB -> 786 MB). LDS 67.6 KB
// keeps 2 blocks/CU.
// ---------------------------------------------------------------------------
__global__ __launch_bounds__(256, 2)
void ff_kernel(const float* __restrict__ state,
               const float* __restrict__ action,
               const float* __restrict__ fc11_b, const float* __restrict__ fc21_b,
               const float* __restrict__ b_hh1, const float* __restrict__ b_ih1,
               const float* __restrict__ b_hh2, const float* __restrict__ b_ih2,
               const short* __restrict__ tab,
               _Float16* __restrict__ pre_out)
{
    __shared__ short X1[128 * 264];       // 67.6 KB bf16, +8 pad per row

    const int tile = blockIdx.x % 500;
    const int br   = blockIdx.x / 500;
    const int tid  = threadIdx.x;
    const int w    = tid >> 6;
    const int lane = tid & 63;
    const int q = lane >> 4, m = lane & 15;
    const int row0 = tile * 128;

    const float* ba = br ? fc21_b : fc11_b;
    const float* bh = br ? b_hh2 : b_hh1;
    const float* bi = br ? b_ih2 : b_ih1;
    const bf16x8* tG1 = (const bf16x8*)tab + (size_t)br * 4096;
    const bf16x8* tG2 = (const bf16x8*)tab + 8192 + (size_t)br * 8192;

    // per-lane bias values (col = nt*16 + m)
    float ba_v[16], bb_v[16];
#pragma unroll
    for (int nt = 0; nt < 16; ++nt) {
        int c = nt * 16 + m;
        ba_v[nt] = ba[c];
        bb_v[nt] = bh[c] + bi[c];
    }

    // GEMM1 a-frags from global X = concat(state[96], action[32]), 2 m-tiles
    bf16x8 af[2][4];
#pragma unroll
    for (int mt = 0; mt < 2; ++mt) {
        const int rw = row0 + 64 * mt + 16 * w + m;   // a-frag row of this lane
#pragma unroll
        for (int ks = 0; ks < 4; ++ks) {
            int k0 = ks * 32 + q * 8;
            const float* src = (k0 < 96) ? (state  + (size_t)rw * 96 + k0)
                                         : (action + (size_t)rw * 32 + (k0 - 96));
            float4 x0 = *(const float4*)src;
            float4 x1 = *(const float4*)(src + 4);
            bf16x8 a;
            a[0] = f2bf(x0.x); a[1] = f2bf(x0.y); a[2] = f2bf(x0.z); a[3] = f2bf(x0.w);
            a[4] = f2bf(x1.x); a[5] = f2bf(x1.y); a[6] = f2bf(x1.z); a[7] = f2bf(x1.w);
            af[mt][ks] = a;
        }
    }

    // GEMM1: X1 = relu(X @ Wa + ba); b-frags loaded once per nt, used 2x
#pragma unroll 4
    for (int nt = 0; nt < 16; ++nt) {
        bf16x8 bf[4];
#pragma unroll
        for (int ks = 0; ks < 4; ++ks) bf[ks] = tG1[(nt * 4 + ks) * 64 + lane];
#pragma unroll
        for (int mt = 0; mt < 2; ++mt) {
            f32x4 acc = {0.f, 0.f, 0.f, 0.f};
#pragma unroll
            for (int ks = 0; ks < 4; ++ks)
                acc = __builtin_amdgcn_mfma_f32_16x16x32_bf16(af[mt][ks], bf[ks], acc, 0, 0, 0);
#pragma unroll
            for (int r = 0; r < 4; ++r) {     // D: col=lane&15, row=q*4+r
                float v = acc[r] + ba_v[nt];
                v = v > 0.f ? v : 0.f;
                X1[(64 * mt + 16 * w + q * 4 + r) * 264 + nt * 16 + m] = f2bf(v);
            }
        }
    }
    // X1 rows for m-tiles of wave w are written and read by THIS wave only ->
    // lgkmcnt ordering suffices; no barrier.

    // GEMM2 a-frags from LDS
    bf16x8 a2[2][8];
#pragma unroll
    for (int mt = 0; mt < 2; ++mt)
#pragma unroll
        for (int ks = 0; ks < 8; ++ks)
            a2[mt][ks] = *(const bf16x8*)&X1[(64 * mt + 16 * w + m) * 264 + ks * 32 + q * 8];

    _Float16* pre = pre_out + (size_t)br * 64000u * 256u;
#pragma unroll 2
    for (int nt = 0; nt < 16; ++nt) {
        bf16x8 bg[8];
#pragma unroll
        for (int ks = 0; ks < 8; ++ks) bg[ks] = tG2[(nt * 8 + ks) * 64 + lane];
#pragma unroll
        for (int mt = 0; mt < 2; ++mt) {
            f32x4 acc = {0.f, 0.f, 0.f, 0.f};
#pragma unroll
            for (int ks = 0; ks < 8; ++ks)
                acc = __builtin_amdgcn_mfma_f32_16x16x32_bf16(a2[mt][ks], bg[ks], acc, 0, 0, 0);
#pragma unroll
            for (int r = 0; r < 4; ++r) {
                float v = acc[r] + bb_v[nt];
                pre[(size_t)(row0 + 64 * mt + 16 * w + q * 4 + r) * 256 + nt * 16 + m] = (_Float16)v;
            }
        }
    }
}

// ---------------------------------------------------------------------------
// Kernel 2: recurrence, split-K across 4 waves, 128 blocks.
// CHANGE vs R7: amdgpu_waves_per_eu(1,1). R7 proved the per-point "+v" pin
// doesn't stop occupancy-driven rematerialization (VGPR stayed 92, VALUBusy
// showed ~3x the fdot2 VALU = per-step weight reload+cvt from L2, ~131 KB/
// CU/step = the 1170-cyc bottleneck). min=max=1 wave/EU removes the
// scheduler's occupancy incentive entirely: full 512-VGPR budget, weights
// stay resident.
// ---------------------------------------------------------------------------
__global__ __launch_bounds__(256)
__attribute__((amdgpu_waves_per_eu(1, 1)))
void rnn_kernel(const _Float16* __restrict__ pre_all,
                const float* __restrict__ hn,
                const float* __restrict__ W_hh1,
                const float* __restrict__ W_hh2,
                _Float16* __restrict__ h_out)
{
    __shared__ _Float16 hbuf[256];
    __shared__ float part[2][4][256];   // [parity][wave][col] = 8 KB

    const int wg = blockIdx.x;          // 0..127
    const int br = wg >> 6;
    const int b  = wg & 63;
    const float* Whh = br ? W_hh2 : W_hh1;
    const _Float16* pre = pre_all + ((size_t)br * 64000u + (size_t)b * 1000u) * 256u;
    _Float16* hg = h_out + ((size_t)br * 64000u + (size_t)b * 1000u) * 256u;

    const int t  = threadIdx.x;
    const int w  = t >> 6;              // wave id = k-slice
    const int l  = t & 63;
    const int k0 = w * 64;
    const int c0 = l * 4;               // 4 columns per lane

    // weights: cols {c0..c0+3} x k in [k0,k0+64), half2 along k, stored as
    // bit-cast uint so the pinning asm constraint is a plain 32-bit VGPR
    unsigned whb[4][32];
#pragma unroll
    for (int i = 0; i < 32; ++i) {
        float4 lo = *(const float4*)(Whh + (size_t)(k0 + 2 * i) * 256 + c0);
        float4 hi = *(const float4*)(Whh + (size_t)(k0 + 2 * i + 1) * 256 + c0);
        whb[0][i] = __builtin_bit_cast(unsigned, half2_t{(_Float16)lo.x, (_Float16)hi.x});
        whb[1][i] = __builtin_bit_cast(unsigned, half2_t{(_Float16)lo.y, (_Float16)hi.y});
        whb[2][i] = __builtin_bit_cast(unsigned, half2_t{(_Float16)lo.z, (_Float16)hi.z});
        whb[3][i] = __builtin_bit_cast(unsigned, half2_t{(_Float16)lo.w, (_Float16)hi.w});
    }
    // PIN: volatile asm "writes" each value -> cannot be re-derived.
#pragma unroll
    for (int c = 0; c < 4; ++c)
#pragma unroll
        for (int i = 0; i < 32; ++i)
            __asm__ __volatile__("" : "+v"(whb[c][i]));

    hbuf[t] = (_Float16)hn[b * 256 + t];
    barrier_lds();

    float pre_c = (float)pre[t];
    float pre_n = (float)pre[256 + t];

    for (int tt = 0; tt < 1000; ++tt) {
        // issue t+2 prefetch early; stays in flight across the barrier
        const int t2 = (tt + 2 < 1000) ? (tt + 2) : 999;
        const float pre_n2 = (float)pre[(size_t)t2 * 256 + t];

        // partial dot over own k-slice, 4 cols, 2 accumulators each
        const float4* hb = (const float4*)&hbuf[k0];
        float sA0 = 0.f, sA1 = 0.f, sA2 = 0.f, sA3 = 0.f;
        float sB0 = 0.f, sB1 = 0.f, sB2 = 0.f, sB3 = 0.f;
#pragma unroll
        for (int k = 0; k < 8; ++k) {
            float4 v = hb[k];                       // 8 halves, wave-broadcast
            const half2_t* hh = (const half2_t*)&v;
#define WH(c, idx) __builtin_bit_cast(half2_t, whb[c][idx])
            sA0 = fdot2(hh[0], WH(0, 4 * k + 0), sA0);
            sA1 = fdot2(hh[0], WH(1, 4 * k + 0), sA1);
            sA2 = fdot2(hh[0], WH(2, 4 * k + 0), sA2);
            sA3 = fdot2(hh[0], WH(3, 4 * k + 0), sA3);
            sA0 = fdot2(hh[1], WH(0, 4 * k + 1), sA0);
            sA1 = fdot2(hh[1], WH(1, 4 * k + 1), sA1);
            sA2 = fdot2(hh[1], WH(2, 4 * k + 1), sA2);
            sA3 = fdot2(hh[1], WH(3, 4 * k + 1), sA3);
            sB0 = fdot2(hh[2], WH(0, 4 * k + 2), sB0);
            sB1 = fdot2(hh[2], WH(1, 4 * k + 2), sB1);
            sB2 = fdot2(hh[2], WH(2, 4 * k + 2), sB2);
            sB3 = fdot2(hh[2], WH(3, 4 * k + 2), sB3);
            sB0 = fdot2(hh[3], WH(0, 4 * k + 3), sB0);
            sB1 = fdot2(hh[3], WH(1, 4 * k + 3), sB1);
            sB2 = fdot2(hh[3], WH(2, 4 * k + 3), sB2);
            sB3 = fdot2(hh[3], WH(3, 4 * k + 3), sB3);
#undef WH
        }
        const int pp = tt & 1;
        *(float4*)&part[pp][w][c0] =
            float4{sA0 + sB0, sA1 + sB1, sA2 + sB2, sA3 + sB3};
        barrier_lds();                              // publish partials

        // reduce col t (wave w owns its own next-step slice)
        const float z = ((part[pp][0][t] + part[pp][1][t]) +
                         (part[pp][2][t] + part[pp][3][t])) + pre_c;
        const float h = 1.0f / (1.0f + __expf(-z));
        const _Float16 h16 = (_Float16)h;
        hbuf[t] = h16;                              // same-wave consumer
        hg[(size_t)tt * 256 + t] = h16;             // in flight across barrier

        pre_c = pre_n;
        pre_n = pre_n2;
    }
}

// ---------------------------------------------------------------------------
// Kernel 3: q head. q[n] = h[n,:] . qw + qb. One thread per output.
// ---------------------------------------------------------------------------
__global__ __launch_bounds__(256, 2)
void q_kernel(const _Float16* __restrict__ h_all,
              const float* __restrict__ fc12_w, const float* __restrict__ fc12_b,
              const float* __restrict__ fc22_w, const float* __restrict__ fc22_b,
              float* __restrict__ out)
{
    const int n  = blockIdx.x * 256 + threadIdx.x;    // 500 blocks -> n < 128000
    const int br = (n >= 64000);                      // block-uniform
    const float* qwp = br ? fc22_w : fc12_w;
    const float  qb  = br ? fc22_b[0] : fc12_b[0];

    half2_t qw[128];
#pragma unroll
    for (int i = 0; i < 128; ++i)
        qw[i] = half2_t{(_Float16)qwp[2 * i], (_Float16)qwp[2 * i + 1]};

    const float4* hr = (const float4*)(h_all + (size_t)n * 256u);
    float s0 = qb, s1 = 0.f, s2 = 0.f, s3 = 0.f;
#pragma unroll
    for (int k = 0; k < 32; ++k) {
        float4 v = hr[k];
        const half2_t* hh = (const half2_t*)&v;
        s0 = fdot2(hh[0], qw[4 * k + 0], s0);
        s1 = fdot2(hh[1], qw[4 * k + 1], s1);
        s2 = fdot2(hh[2], qw[4 * k + 2], s2);
        s3 = fdot2(hh[3], qw[4 * k + 3], s3);
    }
    out[n] = (s0 + s1) + (s2 + s3);
}

// ---------------------------------------------------------------------------
extern "C" void kernel_launch(void* const* d_in, const int* in_sizes, int n_in,
                              void* d_out, int out_size, void* d_ws, size_t ws_size,
                              hipStream_t stream)
{
    const float* state  = (const float*)d_in[0];
    const float* action = (const float*)d_in[1];
    const float* hn     = (const float*)d_in[2];
    const float* fc11_w = (const float*)d_in[3];
    const float* fc11_b = (const float*)d_in[4];
    const float* W_hh1  = (const float*)d_in[5];
    const float* W_ih1  = (const float*)d_in[6];
    const float* b_hh1  = (const float*)d_in[7];
    const float* b_ih1  = (const float*)d_in[8];
    const float* fc12_w = (const float*)d_in[9];
    const float* fc12_b = (const float*)d_in[10];
    const float* fc21_w = (const float*)d_in[11];
    const float* fc21_b = (const float*)d_in[12];
    const float* W_hh2  = (const float*)d_in[13];
    const float* W_ih2  = (const float*)d_in[14];
    const float* b_hh2  = (const float*)d_in[15];
    const float* b_ih2  = (const float*)d_in[16];
    const float* fc22_w = (const float*)d_in[17];
    const float* fc22_b = (const float*)d_in[18];

    _Float16* pre = (_Float16*)d_ws;                         // 65,536,000 B
    _Float16* hbg = (_Float16*)d_ws + 32768000u;             // 65,536,000 B
    short* tab = (short*)((char*)d_ws + 130678784u);         // frag tables (tail of h region)

    prep_kernel<<<96, 256, 0, stream>>>(fc11_w, W_ih1, fc21_w, W_ih2, tab);
    ff_kernel<<<1000, 256, 0, stream>>>(state, action,
                                        fc11_b, fc21_b, b_hh1, b_ih1,
                                        b_hh2, b_ih2, tab, pre);
    rnn_kernel<<<128, 256, 0, stream>>>(pre, hn, W_hh1, W_hh2, hbg);
    q_kernel<<<500, 256, 0, stream>>>(hbg, fc12_w, fc12_b, fc22_w, fc22_b,
                                      (float*)d_out);
}